// Round 5
// baseline (1115.696 us; speedup 1.0000x reference)
//
#include <hip/hip_runtime.h>

#define N_NODES 100000
#define N_EDGES 1600000
#define NB1 391  // ceil(N_NODES/256)

typedef __attribute__((ext_vector_type(8))) short short8;
typedef __attribute__((ext_vector_type(4))) float floatx4;

__device__ inline short bf16_rne(float f) {
    union { float f; unsigned u; } v; v.f = f;
    unsigned r = v.u + 0x7FFF + ((v.u >> 16) & 1);
    return (short)(r >> 16);
}

// ---------------- weight prep: all transposed, bf16, zero-padded ----------------
__global__ __launch_bounds__(256) void wt_kernel(
    const float* __restrict__ Wb, const float* __restrict__ W1,
    const float* __restrict__ W2,
    short* __restrict__ WT, short* __restrict__ W1T, short* __restrict__ W2T)
{
    int i = blockIdx.x * 256 + threadIdx.x;
    if (i < 48 * 512) {
        int m = i >> 9, k = i & 511;
        WT[i] = bf16_rne((m < 40 && k < 500) ? Wb[k * 40 + m] : 0.f);
    }
    if (i < 64 * 64) {
        int m = i >> 6, k = i & 63;
        W1T[i] = bf16_rne((k < 40) ? W1[k * 64 + m] : 0.f);
    }
    if (i < 48 * 64) {
        int m = i >> 6, k = i & 63;
        W2T[i] = bf16_rne((m < 40) ? W2[k * 40 + m] : 0.f);
    }
}

// ---------------- scores = x @ W_base + b_base via MFMA ----------------
__global__ __launch_bounds__(256) void scores_kernel(
    const float* __restrict__ x, const short8* __restrict__ WT8,
    const float* __restrict__ bb, float* __restrict__ scores)
{
    int wave = threadIdx.x >> 6;
    int lane = threadIdx.x & 63;
    int n0 = (blockIdx.x * 4 + wave) * 16;
    if (n0 >= N_NODES) return;
    int n = n0 + (lane & 15);
    int quad = lane >> 4;
    int m = lane & 15;
    const float* xrow = x + (size_t)n * 500 + quad * 8;

    floatx4 acc0 = {0,0,0,0}, acc1 = {0,0,0,0}, acc2 = {0,0,0,0};

    #pragma unroll 5
    for (int ks = 0; ks < 15; ++ks) {
        int k0 = ks * 32;
        float4 xa = *(const float4*)(xrow + k0);
        float4 xb = *(const float4*)(xrow + k0 + 4);
        short8 bf;
        bf[0] = bf16_rne(xa.x); bf[1] = bf16_rne(xa.y);
        bf[2] = bf16_rne(xa.z); bf[3] = bf16_rne(xa.w);
        bf[4] = bf16_rne(xb.x); bf[5] = bf16_rne(xb.y);
        bf[6] = bf16_rne(xb.z); bf[7] = bf16_rne(xb.w);
        int widx = (k0 >> 3) + quad;
        short8 a0 = WT8[(size_t)(0  + m) * 64 + widx];
        short8 a1 = WT8[(size_t)(16 + m) * 64 + widx];
        short8 a2 = WT8[(size_t)(32 + m) * 64 + widx];
        acc0 = __builtin_amdgcn_mfma_f32_16x16x32_bf16(a0, bf, acc0, 0, 0, 0);
        acc1 = __builtin_amdgcn_mfma_f32_16x16x32_bf16(a1, bf, acc1, 0, 0, 0);
        acc2 = __builtin_amdgcn_mfma_f32_16x16x32_bf16(a2, bf, acc2, 0, 0, 0);
    }
    {   // K tail: k = 480+quad*8+j; A rows are zero for k>=500
        int kbase = 480 + quad * 8;
        float4 xa = {0,0,0,0}, xb = {0,0,0,0};
        if (kbase + 8 <= 500) { xa = *(const float4*)(xrow + 480); xb = *(const float4*)(xrow + 484); }
        else if (kbase < 500) { xa = *(const float4*)(xrow + 480); }
        short8 bf;
        bf[0] = bf16_rne(xa.x); bf[1] = bf16_rne(xa.y);
        bf[2] = bf16_rne(xa.z); bf[3] = bf16_rne(xa.w);
        bf[4] = bf16_rne(xb.x); bf[5] = bf16_rne(xb.y);
        bf[6] = bf16_rne(xb.z); bf[7] = bf16_rne(xb.w);
        int widx = 60 + quad;
        short8 a0 = WT8[(size_t)(0  + m) * 64 + widx];
        short8 a1 = WT8[(size_t)(16 + m) * 64 + widx];
        short8 a2 = WT8[(size_t)(32 + m) * 64 + widx];
        acc0 = __builtin_amdgcn_mfma_f32_16x16x32_bf16(a0, bf, acc0, 0, 0, 0);
        acc1 = __builtin_amdgcn_mfma_f32_16x16x32_bf16(a1, bf, acc1, 0, 0, 0);
        acc2 = __builtin_amdgcn_mfma_f32_16x16x32_bf16(a2, bf, acc2, 0, 0, 0);
    }

    float* srow = scores + (size_t)n * 40;
    int mb = quad * 4;
    float4 b4 = *(const float4*)(bb + mb);
    *(float4*)(srow + mb) = make_float4(acc0[0] + b4.x, acc0[1] + b4.y,
                                        acc0[2] + b4.z, acc0[3] + b4.w);
    mb = 16 + quad * 4;
    b4 = *(const float4*)(bb + mb);
    *(float4*)(srow + mb) = make_float4(acc1[0] + b4.x, acc1[1] + b4.y,
                                        acc1[2] + b4.z, acc1[3] + b4.w);
    mb = 32 + quad * 4;
    if (mb < 40) {
        b4 = *(const float4*)(bb + mb);
        *(float4*)(srow + mb) = make_float4(acc2[0] + b4.x, acc2[1] + b4.y,
                                            acc2[2] + b4.z, acc2[3] + b4.w);
    }
}

// ---------------- fused softmax + MLP via MFMA ----------------
__global__ __launch_bounds__(320) void mlp_kernel(
    const float* __restrict__ scores,
    const short8* __restrict__ W1T8, const float* __restrict__ b1,
    const short8* __restrict__ W2T8, const float* __restrict__ b2,
    float* __restrict__ h0)
{
    __shared__ short hs[5][16 * 72];
    int wave = threadIdx.x >> 6;
    int lane = threadIdx.x & 63;
    int q = lane >> 4;
    int n16 = lane & 15;
    int node = (blockIdx.x * 5 + wave) * 16 + n16;

    const float* srow = scores + (size_t)node * 40;
    float4 xa = *(const float4*)(srow + q * 8);
    float4 xb = *(const float4*)(srow + q * 8 + 4);
    float4 xc = {0,0,0,0}, xd = {0,0,0,0};
    if (q == 0) { xc = *(const float4*)(srow + 32); xd = *(const float4*)(srow + 36); }

    float m = fmaxf(fmaxf(fmaxf(xa.x, xa.y), fmaxf(xa.z, xa.w)),
                    fmaxf(fmaxf(xb.x, xb.y), fmaxf(xb.z, xb.w)));
    if (q == 0)
        m = fmaxf(m, fmaxf(fmaxf(fmaxf(xc.x, xc.y), fmaxf(xc.z, xc.w)),
                           fmaxf(fmaxf(xd.x, xd.y), fmaxf(xd.z, xd.w))));
    m = fmaxf(m, __shfl_xor(m, 16));
    m = fmaxf(m, __shfl_xor(m, 32));

    float e0 = __expf(xa.x - m), e1 = __expf(xa.y - m), e2 = __expf(xa.z - m), e3 = __expf(xa.w - m);
    float e4 = __expf(xb.x - m), e5 = __expf(xb.y - m), e6 = __expf(xb.z - m), e7 = __expf(xb.w - m);
    float f0 = 0, f1 = 0, f2 = 0, f3 = 0, f4 = 0, f5 = 0, f6 = 0, f7 = 0;
    if (q == 0) {
        f0 = __expf(xc.x - m); f1 = __expf(xc.y - m); f2 = __expf(xc.z - m); f3 = __expf(xc.w - m);
        f4 = __expf(xd.x - m); f5 = __expf(xd.y - m); f6 = __expf(xd.z - m); f7 = __expf(xd.w - m);
    }
    float sum = e0 + e1 + e2 + e3 + e4 + e5 + e6 + e7 + f0 + f1 + f2 + f3 + f4 + f5 + f6 + f7;
    sum += __shfl_xor(sum, 16);
    sum += __shfl_xor(sum, 32);
    float inv = 1.f / sum;

    short8 bf_a, bf_b;
    bf_a[0] = bf16_rne(e0 * inv); bf_a[1] = bf16_rne(e1 * inv);
    bf_a[2] = bf16_rne(e2 * inv); bf_a[3] = bf16_rne(e3 * inv);
    bf_a[4] = bf16_rne(e4 * inv); bf_a[5] = bf16_rne(e5 * inv);
    bf_a[6] = bf16_rne(e6 * inv); bf_a[7] = bf16_rne(e7 * inv);
    bf_b[0] = bf16_rne(f0 * inv); bf_b[1] = bf16_rne(f1 * inv);
    bf_b[2] = bf16_rne(f2 * inv); bf_b[3] = bf16_rne(f3 * inv);
    bf_b[4] = bf16_rne(f4 * inv); bf_b[5] = bf16_rne(f5 * inv);
    bf_b[6] = bf16_rne(f6 * inv); bf_b[7] = bf16_rne(f7 * inv);

    short* hw = &hs[wave][0];
    #pragma unroll
    for (int t = 0; t < 4; ++t) {
        floatx4 acc = {0, 0, 0, 0};
        short8 A0 = W1T8[(t * 16 + n16) * 8 + q];
        short8 A1 = W1T8[(t * 16 + n16) * 8 + 4 + q];
        acc = __builtin_amdgcn_mfma_f32_16x16x32_bf16(A0, bf_a, acc, 0, 0, 0);
        acc = __builtin_amdgcn_mfma_f32_16x16x32_bf16(A1, bf_b, acc, 0, 0, 0);
        float4 bv = *(const float4*)(b1 + t * 16 + q * 4);
        short4 pk;
        pk.x = bf16_rne(fmaxf(acc[0] + bv.x, 0.f));
        pk.y = bf16_rne(fmaxf(acc[1] + bv.y, 0.f));
        pk.z = bf16_rne(fmaxf(acc[2] + bv.z, 0.f));
        pk.w = bf16_rne(fmaxf(acc[3] + bv.w, 0.f));
        *(short4*)(hw + n16 * 72 + t * 16 + q * 4) = pk;
    }
    __syncthreads();

    short8 h1a = *(const short8*)(hw + n16 * 72 + q * 8);
    short8 h1b = *(const short8*)(hw + n16 * 72 + 32 + q * 8);

    float* orow = h0 + (size_t)node * 40;
    #pragma unroll
    for (int t = 0; t < 3; ++t) {
        floatx4 acc = {0, 0, 0, 0};
        short8 A0 = W2T8[(t * 16 + n16) * 8 + q];
        short8 A1 = W2T8[(t * 16 + n16) * 8 + 4 + q];
        acc = __builtin_amdgcn_mfma_f32_16x16x32_bf16(A0, h1a, acc, 0, 0, 0);
        acc = __builtin_amdgcn_mfma_f32_16x16x32_bf16(A1, h1b, acc, 0, 0, 0);
        int mc = t * 16 + q * 4;
        if (mc < 40) {
            float4 bv = *(const float4*)(b2 + mc);
            *(float4*)(orow + mc) = make_float4(acc[0] + bv.x, acc[1] + bv.y,
                                                acc[2] + bv.z, acc[3] + bv.w);
        }
    }
}

// ---------------- degree count + within-dst rank capture ----------------
__global__ __launch_bounds__(256) void deg_kernel(
    const int* __restrict__ src, const int* __restrict__ dst,
    int* __restrict__ deg_out, int* __restrict__ deg_in, int* __restrict__ rank)
{
    int e = blockIdx.x * 256 + threadIdx.x;
    if (e < N_EDGES) {
        atomicAdd(&deg_out[src[e]], 1);
        rank[e] = atomicAdd(&deg_in[dst[e]], 1);  // old value = rank within dst
    }
}

__global__ __launch_bounds__(256) void inv_kernel(
    const int* __restrict__ deg_out, const int* __restrict__ deg_in,
    float* __restrict__ inv_out, float* __restrict__ inv_in)
{
    int i = blockIdx.x * 256 + threadIdx.x;
    if (i < N_NODES) {
        int a = deg_out[i], b = deg_in[i];
        inv_out[i] = (a > 0) ? rsqrtf((float)a) : 0.f;
        inv_in[i]  = (b > 0) ? rsqrtf((float)b) : 0.f;
    }
}

// ---------------- exclusive scan of deg_in -> row_start ----------------
__global__ __launch_bounds__(256) void scan1_kernel(
    const int* __restrict__ deg_in, int* __restrict__ row_start, int* __restrict__ bsum)
{
    __shared__ int tmp[256];
    int t = threadIdx.x;
    int i = blockIdx.x * 256 + t;
    int v = (i < N_NODES) ? deg_in[i] : 0;
    tmp[t] = v;
    __syncthreads();
    #pragma unroll
    for (int off = 1; off < 256; off <<= 1) {
        int add = (t >= off) ? tmp[t - off] : 0;
        __syncthreads();
        tmp[t] += add;
        __syncthreads();
    }
    if (i < N_NODES) row_start[i] = tmp[t] - v;
    if (t == 255) bsum[blockIdx.x] = tmp[t];
}

__global__ __launch_bounds__(512) void scan2_kernel(int* __restrict__ bsum)
{
    __shared__ int tmp[512];
    int t = threadIdx.x;
    int v = (t < NB1) ? bsum[t] : 0;
    tmp[t] = v;
    __syncthreads();
    #pragma unroll
    for (int off = 1; off < 512; off <<= 1) {
        int add = (t >= off) ? tmp[t - off] : 0;
        __syncthreads();
        tmp[t] += add;
        __syncthreads();
    }
    if (t < NB1) bsum[t] = tmp[t] - v;  // exclusive
}

__global__ __launch_bounds__(256) void scan3_kernel(
    int* __restrict__ row_start, const int* __restrict__ bsum)
{
    int i = blockIdx.x * 256 + threadIdx.x;
    if (i < N_NODES) row_start[i] += bsum[i >> 8];
    if (i == 0) row_start[N_NODES] = N_EDGES;  // sentinel
}

// ---------------- CSR placement (atomic-free) ----------------
__global__ __launch_bounds__(256) void place_kernel(
    const int* __restrict__ src, const int* __restrict__ dst,
    const float* __restrict__ inv_out, const float* __restrict__ inv_in,
    const int* __restrict__ row_start, const int* __restrict__ rank,
    int2* __restrict__ csr)
{
    int e = blockIdx.x * 256 + threadIdx.x;
    if (e < N_EDGES) {
        int s = src[e], d = dst[e];
        int idx = row_start[d] + rank[e];
        float w = 0.9f * inv_out[s] * inv_in[d];
        csr[idx] = make_int2(s * 10, __float_as_int(w));
    }
}

// ---------------- counting sort of nodes by in-degree (64 bins) ----------------
__global__ __launch_bounds__(256) void dhist_kernel(
    const int* __restrict__ deg_in, int* __restrict__ dbins)
{
    __shared__ int lh[64];
    int t = threadIdx.x;
    if (t < 64) lh[t] = 0;
    __syncthreads();
    int i = blockIdx.x * 256 + t;
    if (i < N_NODES) atomicAdd(&lh[min(deg_in[i], 63)], 1);
    __syncthreads();
    if (t < 64 && lh[t]) atomicAdd(&dbins[t], lh[t]);
}

__global__ __launch_bounds__(64) void dscan_kernel(
    const int* __restrict__ dbins, int* __restrict__ dcur)
{
    __shared__ int tmp[64];
    int t = threadIdx.x;
    int v = dbins[t];
    tmp[t] = v;
    __syncthreads();
    #pragma unroll
    for (int off = 1; off < 64; off <<= 1) {
        int add = (t >= off) ? tmp[t - off] : 0;
        __syncthreads();
        tmp[t] += add;
        __syncthreads();
    }
    dcur[t] = tmp[t] - v;  // exclusive start; doubles as running cursor
}

__global__ __launch_bounds__(256) void dplace_kernel(
    const int* __restrict__ deg_in, int* __restrict__ dcur, int* __restrict__ perm)
{
    __shared__ int lh[64];
    __shared__ int lbase[64];
    int t = threadIdx.x;
    if (t < 64) lh[t] = 0;
    __syncthreads();
    int i = blockIdx.x * 256 + t;
    int b = 0, rk = 0;
    if (i < N_NODES) {
        b = min(deg_in[i], 63);
        rk = atomicAdd(&lh[b], 1);
    }
    __syncthreads();
    if (t < 64 && lh[t]) lbase[t] = atomicAdd(&dcur[t], lh[t]);
    __syncthreads();
    if (i < N_NODES) perm[lbase[b] + rk] = i;
}

// ---------------- one APPNP hop: degree-clustered order, unroll-8 ----------------
#define HFMA(W, V) \
    acc.x = fmaf(W, V.x, acc.x); acc.y = fmaf(W, V.y, acc.y); \
    acc.z = fmaf(W, V.z, acc.z); acc.w = fmaf(W, V.w, acc.w);

__global__ __launch_bounds__(256) void hop_kernel(
    const float4* __restrict__ hcur, const float4* __restrict__ h0,
    const int* __restrict__ row_start, const int* __restrict__ perm,
    const int2* __restrict__ csr, float4* __restrict__ hnew)
{
    int gid = blockIdx.x * 256 + threadIdx.x;
    if (gid >= 10 * N_NODES) return;
    int r = gid / 10;
    int q = gid - r * 10;
    int d = perm[r];            // degree-clustered: wave's trip counts ~equal
    int base = d * 10 + q;
    float4 hv0 = h0[base];
    float4 acc = make_float4(0.1f * hv0.x, 0.1f * hv0.y, 0.1f * hv0.z, 0.1f * hv0.w);
    int j   = row_start[d];
    int end = row_start[d + 1];
    for (; j + 8 <= end; j += 8) {
        int2 e0 = csr[j],     e1 = csr[j + 1], e2 = csr[j + 2], e3 = csr[j + 3];
        int2 e4 = csr[j + 4], e5 = csr[j + 5], e6 = csr[j + 6], e7 = csr[j + 7];
        float4 v0 = hcur[e0.x + q], v1 = hcur[e1.x + q];
        float4 v2 = hcur[e2.x + q], v3 = hcur[e3.x + q];
        float4 v4 = hcur[e4.x + q], v5 = hcur[e5.x + q];
        float4 v6 = hcur[e6.x + q], v7 = hcur[e7.x + q];
        HFMA(__int_as_float(e0.y), v0) HFMA(__int_as_float(e1.y), v1)
        HFMA(__int_as_float(e2.y), v2) HFMA(__int_as_float(e3.y), v3)
        HFMA(__int_as_float(e4.y), v4) HFMA(__int_as_float(e5.y), v5)
        HFMA(__int_as_float(e6.y), v6) HFMA(__int_as_float(e7.y), v7)
    }
    for (; j + 2 <= end; j += 2) {
        int2 e0 = csr[j], e1 = csr[j + 1];
        float4 v0 = hcur[e0.x + q], v1 = hcur[e1.x + q];
        HFMA(__int_as_float(e0.y), v0) HFMA(__int_as_float(e1.y), v1)
    }
    if (j < end) {
        int2 e0 = csr[j];
        float4 v0 = hcur[e0.x + q];
        HFMA(__int_as_float(e0.y), v0)
    }
    hnew[base] = acc;
}

extern "C" void kernel_launch(void* const* d_in, const int* in_sizes, int n_in,
                              void* d_out, int out_size, void* d_ws, size_t ws_size,
                              hipStream_t stream) {
    const float* x  = (const float*)d_in[0];
    const int*   ei = (const int*)d_in[1];
    const int*   src = ei;
    const int*   dst = ei + N_EDGES;
    const float* Wb = (const float*)d_in[2];
    const float* bb = (const float*)d_in[3];
    const float* W1 = (const float*)d_in[4];
    const float* b1 = (const float*)d_in[5];
    const float* W2 = (const float*)d_in[6];
    const float* b2 = (const float*)d_in[7];

    float* out_adj    = (float*)d_out;
    float* out_scores = (float*)d_out + 4000000;

    float* h0      = (float*)d_ws;                  // 4,000,000 f
    float* hA      = h0 + 4000000;                  // 4,000,000 f
    int* rank      = (int*)hA;                      // E ints, aliases hA (dead before hops)
    int* deg_out   = (int*)(hA + 4000000);          // N
    int* deg_in    = deg_out + N_NODES;             // N
    int* dbins     = deg_in + N_NODES;              // 64 (zeroed with deg arrays)
    int* dcur      = dbins + 64;                    // 64
    float* inv_out = (float*)(dcur + 64);           // N
    float* inv_in  = inv_out + N_NODES;             // N
    int* row_start = (int*)(inv_in + N_NODES);      // N+1
    int* bsum      = row_start + N_NODES + 16;      // 1024
    int* perm      = bsum + 1024;                   // N
    int2* csr      = (int2*)(perm + N_NODES);       // E int2 (16B-aligned by layout)
    short* WT      = (short*)(csr + N_EDGES);       // 48*512 bf16
    short* W1T     = WT + 48 * 512;                 // 64*64 bf16
    short* W2T     = W1T + 64 * 64;                 // 48*64 bf16

    // zero deg_out, deg_in, dbins (contiguous)
    hipMemsetAsync(deg_out, 0, (2 * N_NODES + 64) * sizeof(int), stream);

    deg_kernel<<<N_EDGES / 256, 256, 0, stream>>>(src, dst, deg_out, deg_in, rank);
    inv_kernel<<<NB1, 256, 0, stream>>>(deg_out, deg_in, inv_out, inv_in);
    scan1_kernel<<<NB1, 256, 0, stream>>>(deg_in, row_start, bsum);
    scan2_kernel<<<1, 512, 0, stream>>>(bsum);
    scan3_kernel<<<NB1, 256, 0, stream>>>(row_start, bsum);
    place_kernel<<<N_EDGES / 256, 256, 0, stream>>>(src, dst, inv_out, inv_in,
                                                    row_start, rank, csr);
    dhist_kernel<<<NB1, 256, 0, stream>>>(deg_in, dbins);
    dscan_kernel<<<1, 64, 0, stream>>>(dbins, dcur);
    dplace_kernel<<<NB1, 256, 0, stream>>>(deg_in, dcur, perm);

    wt_kernel<<<96, 256, 0, stream>>>(Wb, W1, W2, WT, W1T, W2T);
    scores_kernel<<<1563, 256, 0, stream>>>(
        x, (const short8*)WT, bb, out_scores);
    mlp_kernel<<<1250, 320, 0, stream>>>(
        out_scores, (const short8*)W1T, b1, (const short8*)W2T, b2, h0);

    const float* cur = h0;
    for (int k = 0; k < 10; ++k) {
        float* dstbuf = (k & 1) ? out_adj : hA;
        if (k == 9) dstbuf = out_adj;
        hop_kernel<<<(10 * N_NODES + 255) / 256, 256, 0, stream>>>(
            (const float4*)cur, (const float4*)h0, row_start, perm,
            csr, (float4*)dstbuf);
        cur = dstbuf;
    }
}